// Round 15
// baseline (1441.493 us; speedup 1.0000x reference)
//
#include <hip/hip_runtime.h>
#include <cstdint>
#include <cstddef>

// ---------------------------------------------------------------------------
// AdaptiveLSTMBlockWrapper — round 15: R14 + pipelined B in the S engine.
// B fragments double-buffered across the 4 per-kt stages (named even/odd
// register sets, static indexing): each stage prefetches stage+1's B, then
// computes from the set loaded one MFMA-cluster earlier -> L2 latency fully
// covered in-wave. End-of-kt barrier guard = vmcnt(4) (glds retired in-order
// by the s3 compute wait; next-kt B prefetch stays in flight). All other
// code byte-identical to the passing R14 (rotation race-fix, tiered ws).
// ---------------------------------------------------------------------------

typedef _Float16 f16;
typedef f16   f16x8 __attribute__((ext_vector_type(8)));
typedef f16   f16x4 __attribute__((ext_vector_type(4)));
typedef float f32x4 __attribute__((ext_vector_type(4)));

#define TSTEPS 12
#define MBY ((size_t)1 << 20)

// d_out float offsets
#define O_ACC   0u
#define O_H1    4194304u
#define O_C1    8388608u
#define O_H2    12582912u
#define O_C2    16777216u
#define O_PCOST 20971520u
#define O_PSTEP 20971521u

// base3 (R12) ws byte offsets
#define B_C1    ((size_t)0u)
#define B_C2    (16*MBY)
#define B_H1HI  (32*MBY)
#define B_H1LO  (40*MBY)
#define B_H2HI  (48*MBY)
#define B_H2LO  (56*MBY)
#define B_ACTHI (64*MBY)
#define B_ACTLO (72*MBY)
#define B_W2HI  (80*MBY)
#define B_W2LO  (88*MBY)
#define B_W3HI  (96*MBY)
#define B_W3LO  (104*MBY)
#define B_MISC  (112*MBY)
#define B_W4HI  (113*MBY)
#define B_W4LO  (121*MBY)
#define GUARD_W4  (129*MBY)

// rot4 (R13-geom) ws byte offsets
#define R_C1    ((size_t)0u)
#define R_C2    (16*MBY)
#define R_P0    (32*MBY)
#define R_P1    (48*MBY)
#define R_P2    (64*MBY)
#define R_P3    (80*MBY)
#define R_W2HI  (96*MBY)
#define R_W2LO  (104*MBY)
#define R_W3HI  (112*MBY)
#define R_W3LO  (120*MBY)
#define R_MISC  (128*MBY)
#define R_W4HI  (129*MBY)
#define R_W4LO  (137*MBY)
#define GUARD_ROT (146*MBY)

// LDS geometry per engine
#define SEC_ALO_L 32768
#define BUFSZ_L   65536
#define SEC_ALO_S 16384
#define BUFSZ_S   32768

__device__ __forceinline__ float sigmoidf_(float x) { return 1.0f / (1.0f + expf(-x)); }

__device__ __forceinline__ void glds16(const void* g, void* l) {
    __builtin_amdgcn_global_load_lds(
        (const __attribute__((address_space(1))) unsigned int*)g,
        (__attribute__((address_space(3))) unsigned int*)l, 16, 0, 0);
}

__device__ __forceinline__ void block_tile_L(int& m0, int& hc0) {
    const int bid = blockIdx.x;
    const int lid = (bid & 7) * 32 + (bid >> 3);
    m0  = (lid & 15) * 256;
    hc0 = (lid >> 4) * 64;
}
__device__ __forceinline__ void block_tile_S(int& m0, int& hc0) {
    const int bid = blockIdx.x;
    const int lid = (bid & 7) * 64 + (bid >> 3);
    m0  = (lid & 31) * 128;
    hc0 = (lid >> 5) * 64;
}

// ========================= Engine L (R12, 256x256) =========================
template<bool B_PAIR>
__device__ __forceinline__ void passK64_L(
    const f16* __restrict__ Ahi, const f16* __restrict__ Alo,
    const f16* __restrict__ Bhi, const f16* __restrict__ Blo,
    const float* __restrict__ Bf32,
    int m0, int hc0, f32x4 (&acc)[8][4], char* sm)
{
    const int tid = threadIdx.x, lane = tid & 63, wid = tid >> 6;
    const int wm  = (wid >> 2) * 128;
    const int wnb = wid & 3;
    const int l15 = lane & 15, lk = lane >> 4;

    int rbase[8], rx[8];
#pragma unroll
    for (int mf = 0; mf < 8; ++mf) {
        const int row = wm + mf * 16 + l15;
        rbase[mf] = row * 128;
        rx[mf]    = row & 7;
    }

    const int secA = wid >> 2;
    const int j0   = (wid & 3) * 8;
    const int rl = lane >> 3, sl = lane & 7;
    const f16* gaBase = (secA ? Alo : Ahi)
                        + (size_t)(m0 + j0 * 8 + rl) * 1024 + ((sl ^ rl) << 3);
    const int albase0 = secA * SEC_ALO_L + j0 * 1024;

    const float* pB32 = nullptr;
    const f16* pwh = nullptr;
    const f16* pwl = nullptr;
    if constexpr (B_PAIR) {
        const size_t pbase = ((size_t)((hc0 >> 6) * 512 + wnb * 4)) * 512 + (size_t)lane * 8;
        pwh = Bhi + pbase;
        pwl = Blo + pbase;
    } else {
        const int wrow0 = hc0 + wnb * 16 + l15;
        pB32 = Bf32 + (size_t)wrow0 * 1024 + lk * 8;
    }

    f16x8 bh0[4], bl0[4], bh1[4], bl1[4];
    float4 P[8];

    auto issueA = [&](int kt, char* buf) {
#pragma unroll
        for (int i = 0; i < 8; ++i)
            glds16(gaBase + (size_t)i * 8192 + kt * 64, buf + albase0 + i * 1024);
    };
    auto loadBP = [&](int kt, int ks, f16x8 (&H)[4], f16x8 (&L)[4]) {
        const size_t o = (size_t)kt * 16384 + (size_t)ks * 8192;
#pragma unroll
        for (int nf = 0; nf < 4; ++nf) {
            H[nf] = *(const f16x8*)(pwh + o + nf * 512);
            L[nf] = *(const f16x8*)(pwl + o + nf * 512);
        }
    };
    auto loadBM = [&](int kt, int ks) {
#pragma unroll
        for (int nf = 0; nf < 4; ++nf) {
            const float* p = pB32 + (size_t)nf * 1048576 + kt * 64 + ks * 32;
            P[2 * nf]     = *(const float4*)(p);
            P[2 * nf + 1] = *(const float4*)(p + 4);
        }
    };
    auto cvtM = [&](f16x8 (&H)[4], f16x8 (&L)[4]) {
#pragma unroll
        for (int nf = 0; nf < 4; ++nf) {
            const float* f0 = (const float*)&P[2 * nf];
            const float* f1 = (const float*)&P[2 * nf + 1];
            f16x8 h, l;
#pragma unroll
            for (int j = 0; j < 4; ++j) {
                const f16 a = (f16)f0[j];
                h[j] = a; l[j] = (f16)(f0[j] - (float)a);
                const f16 b = (f16)f1[j];
                h[4 + j] = b; l[4 + j] = (f16)(f1[j] - (float)b);
            }
            H[nf] = h; L[nf] = l;
        }
    };
    auto cluster = [&](const f16x8 (&BH)[4], const f16x8 (&BL)[4], int ks, char* bc) {
#pragma unroll
        for (int mg = 0; mg < 4; ++mg) {
            const int o0 = rbase[2 * mg]     + ((((ks << 2) | lk) ^ rx[2 * mg])     << 4);
            const int o1 = rbase[2 * mg + 1] + ((((ks << 2) | lk) ^ rx[2 * mg + 1]) << 4);
            const f16x8 ah0 = *(const f16x8*)(bc + o0);
            const f16x8 al0 = *(const f16x8*)(bc + SEC_ALO_L + o0);
            const f16x8 ah1 = *(const f16x8*)(bc + o1);
            const f16x8 al1 = *(const f16x8*)(bc + SEC_ALO_L + o1);
            __builtin_amdgcn_s_setprio(1);
#pragma unroll
            for (int nf = 0; nf < 4; ++nf) {
                acc[2 * mg][nf]     = __builtin_amdgcn_mfma_f32_16x16x32_f16(ah0, BH[nf], acc[2 * mg][nf], 0, 0, 0);
                acc[2 * mg + 1][nf] = __builtin_amdgcn_mfma_f32_16x16x32_f16(ah1, BH[nf], acc[2 * mg + 1][nf], 0, 0, 0);
            }
#pragma unroll
            for (int nf = 0; nf < 4; ++nf) {
                acc[2 * mg][nf]     = __builtin_amdgcn_mfma_f32_16x16x32_f16(ah0, BL[nf], acc[2 * mg][nf], 0, 0, 0);
                acc[2 * mg + 1][nf] = __builtin_amdgcn_mfma_f32_16x16x32_f16(ah1, BL[nf], acc[2 * mg + 1][nf], 0, 0, 0);
            }
#pragma unroll
            for (int nf = 0; nf < 4; ++nf) {
                acc[2 * mg][nf]     = __builtin_amdgcn_mfma_f32_16x16x32_f16(al0, BH[nf], acc[2 * mg][nf], 0, 0, 0);
                acc[2 * mg + 1][nf] = __builtin_amdgcn_mfma_f32_16x16x32_f16(al1, BH[nf], acc[2 * mg + 1][nf], 0, 0, 0);
            }
            __builtin_amdgcn_s_setprio(0);
        }
    };

    if constexpr (B_PAIR) loadBP(0, 0, bh0, bl0);
    else                  loadBM(0, 0);
    issueA(0, sm);
    asm volatile("s_waitcnt vmcnt(0)" ::: "memory");
    __builtin_amdgcn_s_barrier();
    asm volatile("" ::: "memory");

#pragma unroll 1
    for (int kt = 0; kt < 16; ++kt) {
        char* bc = sm + (kt & 1) * BUFSZ_L;
        char* bn = sm + ((kt + 1) & 1) * BUFSZ_L;
        const bool pre = (kt < 15);

        if constexpr (B_PAIR) {
            loadBP(kt, 1, bh1, bl1);
            if (pre) issueA(kt + 1, bn);
            cluster(bh0, bl0, 0, bc);
            if (pre) asm volatile("s_waitcnt vmcnt(8)" ::: "memory");
            else     asm volatile("s_waitcnt vmcnt(0)" ::: "memory");
            if (pre) loadBP(kt + 1, 0, bh0, bl0);
            cluster(bh1, bl1, 1, bc);
        } else {
            cvtM(bh0, bl0);
            loadBM(kt, 1);
            if (pre) issueA(kt + 1, bn);
            cluster(bh0, bl0, 0, bc);
            if (pre) asm volatile("s_waitcnt vmcnt(8)" ::: "memory");
            else     asm volatile("s_waitcnt vmcnt(0)" ::: "memory");
            cvtM(bh0, bl0);
            if (pre) loadBM(kt + 1, 0);
            cluster(bh0, bl0, 1, bc);
        }
        if (pre) {
            asm volatile("s_waitcnt vmcnt(8)" ::: "memory");
            __builtin_amdgcn_s_barrier();
            asm volatile("" ::: "memory");
        } else {
            asm volatile("s_waitcnt vmcnt(0)" ::: "memory");
        }
    }
}

// ============== Engine S (128x256, pipelined packed-B stages) ==============
__device__ __forceinline__ void passS(
    const f16* __restrict__ Ahi, const f16* __restrict__ Alo,
    const f16* __restrict__ Bhi, const f16* __restrict__ Blo,
    int m0, int hc0, f32x4 (&acc)[4][4], char* sm)
{
    const int tid = threadIdx.x, lane = tid & 63, wid = tid >> 6;
    const int wm  = (wid >> 2) * 64;
    const int wnb = wid & 3;
    const int l15 = lane & 15, lk = lane >> 4;

    int rbase[4], rx[4];
#pragma unroll
    for (int mf = 0; mf < 4; ++mf) {
        const int row = wm + mf * 16 + l15;
        rbase[mf] = row * 128;
        rx[mf]    = row & 7;
    }

    const int secA = wid >> 2;
    const int j0   = (wid & 3) * 4;
    const int rl = lane >> 3, sl = lane & 7;
    const f16* gaBase = (secA ? Alo : Ahi)
                        + (size_t)(m0 + j0 * 8 + rl) * 1024 + ((sl ^ rl) << 3);
    const int lb0 = secA * SEC_ALO_S + j0 * 1024;

    const size_t pbase = ((size_t)((hc0 >> 6) * 512 + wnb * 4)) * 512 + (size_t)lane * 8;
    const f16* pwh = Bhi + pbase;
    const f16* pwl = Blo + pbase;

    // two named B register sets (static indexing; rule #20)
    f16x8 BH0[2], BL0[2], BH1[2], BL1[2];

    auto issueA = [&](int kt, char* buf) {
#pragma unroll
        for (int i = 0; i < 4; ++i)
            glds16(gaBase + (size_t)i * 8192 + kt * 64, buf + lb0 + i * 1024);
    };
    auto loadB = [&](int kt, int ks, int np, f16x8 (&H)[2], f16x8 (&L)[2]) {
#pragma unroll
        for (int q = 0; q < 2; ++q) {
            const size_t bo = (size_t)kt * 16384 + (size_t)ks * 8192
                            + (size_t)(2 * np + q) * 512;
            H[q] = *(const f16x8*)(pwh + bo);
            L[q] = *(const f16x8*)(pwl + bo);
        }
    };
    auto clusterS = [&](const f16x8 (&BH)[2], const f16x8 (&BL)[2],
                        int ks, int np, char* bc) {
#pragma unroll
        for (int mg = 0; mg < 2; ++mg) {
            const int o0 = rbase[2 * mg]     + ((((ks << 2) | lk) ^ rx[2 * mg])     << 4);
            const int o1 = rbase[2 * mg + 1] + ((((ks << 2) | lk) ^ rx[2 * mg + 1]) << 4);
            const f16x8 ah0 = *(const f16x8*)(bc + o0);
            const f16x8 al0 = *(const f16x8*)(bc + SEC_ALO_S + o0);
            const f16x8 ah1 = *(const f16x8*)(bc + o1);
            const f16x8 al1 = *(const f16x8*)(bc + SEC_ALO_S + o1);
            __builtin_amdgcn_s_setprio(1);
#pragma unroll
            for (int q = 0; q < 2; ++q) {
                acc[2 * mg][2 * np + q]     = __builtin_amdgcn_mfma_f32_16x16x32_f16(ah0, BH[q], acc[2 * mg][2 * np + q], 0, 0, 0);
                acc[2 * mg + 1][2 * np + q] = __builtin_amdgcn_mfma_f32_16x16x32_f16(ah1, BH[q], acc[2 * mg + 1][2 * np + q], 0, 0, 0);
            }
#pragma unroll
            for (int q = 0; q < 2; ++q) {
                acc[2 * mg][2 * np + q]     = __builtin_amdgcn_mfma_f32_16x16x32_f16(ah0, BL[q], acc[2 * mg][2 * np + q], 0, 0, 0);
                acc[2 * mg + 1][2 * np + q] = __builtin_amdgcn_mfma_f32_16x16x32_f16(ah1, BL[q], acc[2 * mg + 1][2 * np + q], 0, 0, 0);
            }
#pragma unroll
            for (int q = 0; q < 2; ++q) {
                acc[2 * mg][2 * np + q]     = __builtin_amdgcn_mfma_f32_16x16x32_f16(al0, BH[q], acc[2 * mg][2 * np + q], 0, 0, 0);
                acc[2 * mg + 1][2 * np + q] = __builtin_amdgcn_mfma_f32_16x16x32_f16(al1, BH[q], acc[2 * mg + 1][2 * np + q], 0, 0, 0);
            }
            __builtin_amdgcn_s_setprio(0);
        }
    };

    // ---- prologue: A(kt0) staged; B stage0 -> set0 ----
    issueA(0, sm);
    loadB(0, 0, 0, BH0, BL0);
    asm volatile("s_waitcnt vmcnt(0)" ::: "memory");
    __builtin_amdgcn_s_barrier();
    asm volatile("" ::: "memory");

#pragma unroll 1
    for (int kt = 0; kt < 16; ++kt) {
        char* bc = sm + (kt & 1) * BUFSZ_S;
        char* bn = sm + ((kt + 1) & 1) * BUFSZ_S;
        const bool pre = (kt < 15);
        if (pre) issueA(kt + 1, bn);

        // 4 stages, B pipelined one stage ahead (even->set0, odd->set1)
        loadB(kt, 0, 1, BH1, BL1);            // prefetch s1
        clusterS(BH0, BL0, 0, 0, bc);         // s0 (loaded last kt / prologue)
        loadB(kt, 1, 0, BH0, BL0);            // prefetch s2
        clusterS(BH1, BL1, 0, 1, bc);         // s1
        loadB(kt, 1, 1, BH1, BL1);            // prefetch s3
        clusterS(BH0, BL0, 1, 0, bc);         // s2
        if (pre) loadB(kt + 1, 0, 0, BH0, BL0);  // prefetch next-kt s0
        clusterS(BH1, BL1, 1, 1, bc);         // s3 (wait here retires glds)

        if (pre) {
            asm volatile("s_waitcnt vmcnt(4)" ::: "memory");  // keep prefetch live
            __builtin_amdgcn_s_barrier();
            asm volatile("" ::: "memory");
        } else {
            asm volatile("s_waitcnt vmcnt(0)" ::: "memory");
        }
    }
}

// ====================== LSTM epilogue helpers (inline) =====================
__device__ __forceinline__ void cellA_epi(
    float p0, float p1, float p2, float p3, int idx, int step,
    float* __restrict__ c1,
    f16* __restrict__ h1ohi, f16* __restrict__ h1olo,
    f16* __restrict__ acthi, f16* __restrict__ actlo)
{
    const float ig = sigmoidf_(p0);
    const float fg = sigmoidf_(p1);
    const float gg = tanhf(p2);
    const float og = sigmoidf_(p3);
    const float cold = (step == 0) ? 0.0f : c1[idx];
    const float cn = fg * cold + ig * gg;
    c1[idx] = cn;
    const float h = og * tanhf(cn);
    const f16 hh = (f16)h;
    const f16 hl = (f16)(h - (float)hh);
    h1ohi[idx] = hh; h1olo[idx] = hl;
    const bool pos = h > 0.0f;
    acthi[idx] = pos ? hh : (f16)0.0f;
    actlo[idx] = pos ? hl : (f16)0.0f;
}
__device__ __forceinline__ void cellB_epi(
    float p0, float p1, float p2, float p3, int idx, int step,
    float* __restrict__ c2,
    f16* __restrict__ h2ohi, f16* __restrict__ h2olo)
{
    const float ig = sigmoidf_(p0);
    const float fg = sigmoidf_(p1);
    const float gg = tanhf(p2);
    const float og = sigmoidf_(p3);
    const float cold = (step == 0) ? 0.0f : c2[idx];
    const float cn = fg * cold + ig * gg;
    c2[idx] = cn;
    const float h = og * tanhf(cn);
    const f16 hh = (f16)h;
    h2ohi[idx] = hh;
    h2olo[idx] = (f16)(h - (float)hh);
}

// ============================ L kernels (R12) ==============================
__global__ __launch_bounds__(512, 2) void k_z1_L(
    const f16* __restrict__ xhi, const f16* __restrict__ xlo,
    const f16* __restrict__ W1hi, const f16* __restrict__ W1lo,
    const float* __restrict__ bih1, const float* __restrict__ bhh1,
    float* __restrict__ Z1)
{
    __shared__ __align__(16) char sm[2 * BUFSZ_L];
    int m0, hc0; block_tile_L(m0, hc0);
    f32x4 acc[8][4];
#pragma unroll
    for (int a = 0; a < 8; ++a)
#pragma unroll
        for (int b = 0; b < 4; ++b) acc[a][b] = (f32x4){0.f, 0.f, 0.f, 0.f};
    passK64_L<true>(xhi, xlo, W1hi, W1lo, nullptr, m0, hc0, acc, sm);

    const int tid = threadIdx.x, lane = tid & 63, wid = tid >> 6;
    const int wm = (wid >> 2) * 128, wnb = wid & 3, l15 = lane & 15, lk = lane >> 4;
    const int hc = hc0 + wnb * 16 + l15;
#pragma unroll
    for (int mf = 0; mf < 8; ++mf)
#pragma unroll
        for (int r = 0; r < 4; ++r) {
            const int row = m0 + wm + mf * 16 + lk * 4 + r;
#pragma unroll
            for (int g = 0; g < 4; ++g) {
                const int R = g * 1024 + hc;
                Z1[(size_t)row * 4096 + R] = acc[mf][g][r] + bih1[R] + bhh1[R];
            }
        }
}

template<bool PACKED>
__global__ __launch_bounds__(512, 2) void k_stepA_L(
    const float* __restrict__ Z1, const float* __restrict__ Whh1,
    const f16* __restrict__ W4hi, const f16* __restrict__ W4lo,
    const float* __restrict__ flagcol, float* __restrict__ c1,
    const f16* __restrict__ h1ihi, const f16* __restrict__ h1ilo,
    f16* __restrict__ h1ohi, f16* __restrict__ h1olo,
    f16* __restrict__ acthi, f16* __restrict__ actlo,
    const unsigned* __restrict__ cnt_prev, int step)
{
    if (step > 0 && cnt_prev[0] == 0u) return;
    __shared__ __align__(16) char sm[2 * BUFSZ_L];
    int m0, hc0; block_tile_L(m0, hc0);
    f32x4 acc[8][4];
#pragma unroll
    for (int a = 0; a < 8; ++a)
#pragma unroll
        for (int b = 0; b < 4; ++b) acc[a][b] = (f32x4){0.f, 0.f, 0.f, 0.f};
    if (step > 0) {
        if constexpr (PACKED)
            passK64_L<true>(h1ihi, h1ilo, W4hi, W4lo, nullptr, m0, hc0, acc, sm);
        else
            passK64_L<false>(h1ihi, h1ilo, nullptr, nullptr, Whh1, m0, hc0, acc, sm);
    }

    const int tid = threadIdx.x, lane = tid & 63, wid = tid >> 6;
    const int wm = (wid >> 2) * 128, wnb = wid & 3, l15 = lane & 15, lk = lane >> 4;
    const int hc = hc0 + wnb * 16 + l15;
#pragma unroll
    for (int mf = 0; mf < 8; ++mf)
#pragma unroll
        for (int r = 0; r < 4; ++r) {
            const int row = m0 + wm + mf * 16 + lk * 4 + r;
            float p[4];
#pragma unroll
            for (int g = 0; g < 4; ++g) {
                const int R = g * 1024 + hc;
                p[g] = acc[mf][g][r] + Z1[(size_t)row * 4096 + R];
                if (step == 0) p[g] += flagcol[R];
            }
            cellA_epi(p[0], p[1], p[2], p[3], row * 1024 + hc, step,
                      c1, h1ohi, h1olo, acthi, actlo);
        }
}

__global__ __launch_bounds__(512, 2) void k_stepB_L(
    const f16* __restrict__ acthi, const f16* __restrict__ actlo,
    const f16* __restrict__ W2hi, const f16* __restrict__ W2lo,
    const f16* __restrict__ h2ihi, const f16* __restrict__ h2ilo,
    f16* __restrict__ h2ohi, f16* __restrict__ h2olo,
    const f16* __restrict__ W3hi, const f16* __restrict__ W3lo,
    const float* __restrict__ bih2, const float* __restrict__ bhh2,
    float* __restrict__ c2,
    const unsigned* __restrict__ cnt_prev, int step)
{
    if (step > 0 && cnt_prev[0] == 0u) return;
    __shared__ __align__(16) char sm[2 * BUFSZ_L];
    int m0, hc0; block_tile_L(m0, hc0);
    f32x4 acc[8][4];
#pragma unroll
    for (int a = 0; a < 8; ++a)
#pragma unroll
        for (int b = 0; b < 4; ++b) acc[a][b] = (f32x4){0.f, 0.f, 0.f, 0.f};
    passK64_L<true>(acthi, actlo, W2hi, W2lo, nullptr, m0, hc0, acc, sm);
    if (step > 0)
        passK64_L<true>(h2ihi, h2ilo, W3hi, W3lo, nullptr, m0, hc0, acc, sm);

    const int tid = threadIdx.x, lane = tid & 63, wid = tid >> 6;
    const int wm = (wid >> 2) * 128, wnb = wid & 3, l15 = lane & 15, lk = lane >> 4;
    const int hc = hc0 + wnb * 16 + l15;
#pragma unroll
    for (int mf = 0; mf < 8; ++mf)
#pragma unroll
        for (int r = 0; r < 4; ++r) {
            const int row = m0 + wm + mf * 16 + lk * 4 + r;
            float p[4];
#pragma unroll
            for (int g = 0; g < 4; ++g) {
                const int R = g * 1024 + hc;
                p[g] = acc[mf][g][r] + bih2[R] + bhh2[R];
            }
            cellB_epi(p[0], p[1], p[2], p[3], row * 1024 + hc, step, c2, h2ohi, h2olo);
        }
}

// ============================ S kernels ====================================
__global__ __launch_bounds__(512, 4) void k_z1_S(
    const f16* __restrict__ xhi, const f16* __restrict__ xlo,
    const f16* __restrict__ W1hi, const f16* __restrict__ W1lo,
    const float* __restrict__ bih1, const float* __restrict__ bhh1,
    float* __restrict__ Z1)
{
    __shared__ __align__(16) char sm[2 * BUFSZ_S];
    int m0, hc0; block_tile_S(m0, hc0);
    f32x4 acc[4][4];
#pragma unroll
    for (int a = 0; a < 4; ++a)
#pragma unroll
        for (int b = 0; b < 4; ++b) acc[a][b] = (f32x4){0.f, 0.f, 0.f, 0.f};
    passS(xhi, xlo, W1hi, W1lo, m0, hc0, acc, sm);

    const int tid = threadIdx.x, lane = tid & 63, wid = tid >> 6;
    const int wm = (wid >> 2) * 64, wnb = wid & 3, l15 = lane & 15, lk = lane >> 4;
    const int hc = hc0 + wnb * 16 + l15;
#pragma unroll
    for (int mf = 0; mf < 4; ++mf)
#pragma unroll
        for (int r = 0; r < 4; ++r) {
            const int row = m0 + wm + mf * 16 + lk * 4 + r;
#pragma unroll
            for (int g = 0; g < 4; ++g) {
                const int R = g * 1024 + hc;
                Z1[(size_t)row * 4096 + R] = acc[mf][g][r] + bih1[R] + bhh1[R];
            }
        }
}

__global__ __launch_bounds__(512, 4) void k_stepA_S(
    const float* __restrict__ Z1,
    const f16* __restrict__ W4hi, const f16* __restrict__ W4lo,
    const float* __restrict__ flagcol, float* __restrict__ c1,
    const f16* __restrict__ h1ihi, const f16* __restrict__ h1ilo,
    f16* __restrict__ h1ohi, f16* __restrict__ h1olo,
    f16* __restrict__ acthi, f16* __restrict__ actlo,
    const unsigned* __restrict__ cnt_prev, int step)
{
    if (step > 0 && cnt_prev[0] == 0u) return;
    __shared__ __align__(16) char sm[2 * BUFSZ_S];
    int m0, hc0; block_tile_S(m0, hc0);
    f32x4 acc[4][4];
#pragma unroll
    for (int a = 0; a < 4; ++a)
#pragma unroll
        for (int b = 0; b < 4; ++b) acc[a][b] = (f32x4){0.f, 0.f, 0.f, 0.f};
    if (step > 0)
        passS(h1ihi, h1ilo, W4hi, W4lo, m0, hc0, acc, sm);

    const int tid = threadIdx.x, lane = tid & 63, wid = tid >> 6;
    const int wm = (wid >> 2) * 64, wnb = wid & 3, l15 = lane & 15, lk = lane >> 4;
    const int hc = hc0 + wnb * 16 + l15;
#pragma unroll
    for (int mf = 0; mf < 4; ++mf)
#pragma unroll
        for (int r = 0; r < 4; ++r) {
            const int row = m0 + wm + mf * 16 + lk * 4 + r;
            float p[4];
#pragma unroll
            for (int g = 0; g < 4; ++g) {
                const int R = g * 1024 + hc;
                p[g] = acc[mf][g][r] + Z1[(size_t)row * 4096 + R];
                if (step == 0) p[g] += flagcol[R];
            }
            cellA_epi(p[0], p[1], p[2], p[3], row * 1024 + hc, step,
                      c1, h1ohi, h1olo, acthi, actlo);
        }
}

__global__ __launch_bounds__(512, 4) void k_stepB_S(
    const f16* __restrict__ acthi, const f16* __restrict__ actlo,
    const f16* __restrict__ W2hi, const f16* __restrict__ W2lo,
    const f16* __restrict__ h2ihi, const f16* __restrict__ h2ilo,
    f16* __restrict__ h2ohi, f16* __restrict__ h2olo,
    const f16* __restrict__ W3hi, const f16* __restrict__ W3lo,
    const float* __restrict__ bih2, const float* __restrict__ bhh2,
    float* __restrict__ c2,
    const unsigned* __restrict__ cnt_prev, int step)
{
    if (step > 0 && cnt_prev[0] == 0u) return;
    __shared__ __align__(16) char sm[2 * BUFSZ_S];
    int m0, hc0; block_tile_S(m0, hc0);
    f32x4 acc[4][4];
#pragma unroll
    for (int a = 0; a < 4; ++a)
#pragma unroll
        for (int b = 0; b < 4; ++b) acc[a][b] = (f32x4){0.f, 0.f, 0.f, 0.f};
    passS(acthi, actlo, W2hi, W2lo, m0, hc0, acc, sm);
    if (step > 0)
        passS(h2ihi, h2ilo, W3hi, W3lo, m0, hc0, acc, sm);

    const int tid = threadIdx.x, lane = tid & 63, wid = tid >> 6;
    const int wm = (wid >> 2) * 64, wnb = wid & 3, l15 = lane & 15, lk = lane >> 4;
    const int hc = hc0 + wnb * 16 + l15;
#pragma unroll
    for (int mf = 0; mf < 4; ++mf)
#pragma unroll
        for (int r = 0; r < 4; ++r) {
            const int row = m0 + wm + mf * 16 + lk * 4 + r;
            float p[4];
#pragma unroll
            for (int g = 0; g < 4; ++g) {
                const int R = g * 1024 + hc;
                p[g] = acc[mf][g][r] + bih2[R] + bhh2[R];
            }
            cellB_epi(p[0], p[1], p[2], p[3], row * 1024 + hc, step, c2, h2ohi, h2olo);
        }
}

// ============================ shared kernels ===============================
__global__ __launch_bounds__(256) void k_haltacc(
    const f16* __restrict__ h2hi, const f16* __restrict__ h2lo,
    const float* __restrict__ Whalt, const float* __restrict__ bhalt,
    float* __restrict__ halt, float* __restrict__ cont,
    float* __restrict__ ponder_out, unsigned* __restrict__ ctrl,
    float* __restrict__ acc_out,
    const unsigned* __restrict__ cnt_prev, int step)
{
    if (step > 0 && cnt_prev[0] == 0u) return;
    const int lane = threadIdx.x & 63;
    const int b = blockIdx.x * 4 + (threadIdx.x >> 6);
    const size_t base = (size_t)b * 1024;
    float sum = 0.0f;
    for (int k = lane; k < 1024; k += 64)
        sum += ((float)h2hi[base + k] + (float)h2lo[base + k]) * Whalt[k];
#pragma unroll
    for (int off = 32; off > 0; off >>= 1) sum += __shfl_down(sum, off, 64);
    float co = 0.0f;
    if (lane == 0) {
        const float sh = sigmoidf_(sum + bhalt[0]);
        if (cont[b] != 0.0f) {
            const float hn = halt[b] + sh;
            const bool ending = hn > 0.99f;
            co = sh + (ending ? (1.0f - hn) : 0.0f);
            halt[b] = hn;
            if (!ending) {
                ponder_out[b] += 1.0f;
                atomicAdd(&ctrl[step], 1u);
            } else {
                cont[b] = 0.0f;
            }
        }
        if (b == 0) ctrl[12] = (unsigned)(step + 1);
    }
    co = __shfl(co, 0, 64);
    if (step == 0 || co != 0.0f) {
        float4* dst = (float4*)(acc_out + base);
        const f16x4* hi4 = (const f16x4*)(h2hi + base);
        const f16x4* lo4 = (const f16x4*)(h2lo + base);
#pragma unroll
        for (int j = 0; j < 4; ++j) {
            const int i = lane + 64 * j;
            const f16x4 hv = hi4[i];
            const f16x4 lv = lo4[i];
            float4 d = (step == 0) ? (float4){0.f, 0.f, 0.f, 0.f} : dst[i];
            d.x = fmaf(co, (float)hv[0] + (float)lv[0], d.x);
            d.y = fmaf(co, (float)hv[1] + (float)lv[1], d.y);
            d.z = fmaf(co, (float)hv[2] + (float)lv[2], d.z);
            d.w = fmaf(co, (float)hv[3] + (float)lv[3], d.w);
            dst[i] = d;
        }
    }
}

__global__ __launch_bounds__(256) void k_small_init(
    float* __restrict__ halt, float* __restrict__ cont,
    float* __restrict__ ponder_out, unsigned* __restrict__ ctrl)
{
    const int b = blockIdx.x * 256 + threadIdx.x;
    if (b < 4096) { halt[b] = 0.0f; cont[b] = 1.0f; ponder_out[b] = 0.0f; }
    if (b < 16) ctrl[b] = 0u;
}

__global__ __launch_bounds__(256) void k_split_flat(
    const float* __restrict__ src, f16* __restrict__ hi, f16* __restrict__ lo)
{
    const size_t i = ((size_t)blockIdx.x * 256 + threadIdx.x) * 4;
    const float4 v = *(const float4*)(src + i);
    const f16 s0 = (f16)v.x, s1 = (f16)v.y, s2 = (f16)v.z, s3 = (f16)v.w;
    const f16x4 hv = {s0, s1, s2, s3};
    const f16x4 lw = {(f16)(v.x - (float)s0), (f16)(v.y - (float)s1),
                      (f16)(v.z - (float)s2), (f16)(v.w - (float)s3)};
    *(f16x4*)(hi + i) = hv;
    *(f16x4*)(lo + i) = lw;
}

__global__ __launch_bounds__(256) void k_pack_w(
    const float* __restrict__ src, f16* __restrict__ hi, f16* __restrict__ lo,
    int stride)
{
    const size_t t = (size_t)blockIdx.x * 256 + threadIdx.x;
    const int lane = (int)(t & 63);
    const size_t C = t >> 6;
    const int nf  = (int)(C & 3);
    const int wnb = (int)((C >> 2) & 3);
    const int ks  = (int)((C >> 4) & 1);
    const int kt  = (int)((C >> 5) & 15);
    const int T   = (int)(C >> 9);
    const int row = nf * 1024 + T * 64 + wnb * 16 + (lane & 15);
    const int k0  = kt * 64 + ks * 32 + (lane >> 4) * 8;
    const float* s = src + (size_t)row * stride + k0;
    f16x8 h, l;
#pragma unroll
    for (int j = 0; j < 8; ++j) {
        const float v = s[j];
        const f16 a = (f16)v;
        h[j] = a; l[j] = (f16)(v - (float)a);
    }
    *(f16x8*)(hi + t * 8) = h;
    *(f16x8*)(lo + t * 8) = l;
}

__global__ __launch_bounds__(256) void k_flagcol(
    const float* __restrict__ Wih1, float* __restrict__ flagcol)
{
    const int r = blockIdx.x * 256 + threadIdx.x;
    if (r < 4096) flagcol[r] = Wih1[(size_t)r * 1025 + 1024];
}

__global__ __launch_bounds__(256) void k_fin1(
    const f16* __restrict__ a0h, const f16* __restrict__ a0l,
    const f16* __restrict__ a1h, const f16* __restrict__ a1l,
    const f16* __restrict__ a2h, const f16* __restrict__ a2l,
    const float* __restrict__ c1s, const float* __restrict__ c2s,
    const float* __restrict__ halt, const float* __restrict__ cont,
    const unsigned* __restrict__ ctrl, float* __restrict__ out)
{
    const int j = ((int)ctrl[12] - 1) % 3;
    const f16* h1h = (j == 0) ? a2h : (j == 1) ? a1h : a0h;
    const f16* h1l = (j == 0) ? a2l : (j == 1) ? a1l : a0l;
    const f16* h2h = (j == 0) ? a0h : (j == 1) ? a2h : a1h;
    const f16* h2l = (j == 0) ? a0l : (j == 1) ? a2l : a1l;
    const int b = blockIdx.x;
    const float rem = (cont[b] != 0.0f) ? (1.0f - halt[b]) : 0.0f;
    const int base = b * 1024;
    for (int i = threadIdx.x; i < 1024; i += 256) {
        const float h1v = (float)h1h[base + i] + (float)h1l[base + i];
        const float h2v = (float)h2h[base + i] + (float)h2l[base + i];
        out[O_H1 + base + i] = h1v;
        out[O_C1 + base + i] = c1s[base + i];
        out[O_H2 + base + i] = h2v;
        out[O_C2 + base + i] = c2s[base + i];
        if (rem != 0.0f) out[O_ACC + base + i] += rem * h2v;
    }
}

__global__ __launch_bounds__(256) void k_fin1_flat(
    const f16* __restrict__ h1h, const f16* __restrict__ h1l,
    const f16* __restrict__ h2h, const f16* __restrict__ h2l,
    const float* __restrict__ c1s, const float* __restrict__ c2s,
    const float* __restrict__ halt, const float* __restrict__ cont,
    float* __restrict__ out)
{
    const int b = blockIdx.x;
    const float rem = (cont[b] != 0.0f) ? (1.0f - halt[b]) : 0.0f;
    const int base = b * 1024;
    for (int i = threadIdx.x; i < 1024; i += 256) {
        const float h1v = (float)h1h[base + i] + (float)h1l[base + i];
        const float h2v = (float)h2h[base + i] + (float)h2l[base + i];
        out[O_H1 + base + i] = h1v;
        out[O_C1 + base + i] = c1s[base + i];
        out[O_H2 + base + i] = h2v;
        out[O_C2 + base + i] = c2s[base + i];
        if (rem != 0.0f) out[O_ACC + base + i] += rem * h2v;
    }
}

__global__ __launch_bounds__(256) void k_fin2(
    const float* __restrict__ halt, float* __restrict__ out)
{
    __shared__ float red[256];
    float s = 0.0f;
    for (int i = threadIdx.x; i < 4096; i += 256) s += halt[i];
    red[threadIdx.x] = s;
    __syncthreads();
    for (int w = 128; w > 0; w >>= 1) {
        if (threadIdx.x < w) red[threadIdx.x] += red[threadIdx.x + w];
        __syncthreads();
    }
    if (threadIdx.x == 0) out[O_PCOST] = -0.01f * (red[0] * (1.0f / 4096.0f));
}

// ================================= host ====================================
extern "C" void kernel_launch(void* const* d_in, const int* in_sizes, int n_in,
                              void* d_out, int out_size, void* d_ws, size_t ws_size,
                              hipStream_t stream) {
    const float* inputs = (const float*)d_in[0];
    const float* W_ih1  = (const float*)d_in[1];
    const float* W_hh1  = (const float*)d_in[2];
    const float* b_ih1  = (const float*)d_in[3];
    const float* b_hh1  = (const float*)d_in[4];
    const float* W_ih2  = (const float*)d_in[5];
    const float* W_hh2  = (const float*)d_in[6];
    const float* b_ih2  = (const float*)d_in[7];
    const float* b_hh2  = (const float*)d_in[8];
    const float* W_halt = (const float*)d_in[9];
    const float* b_halt = (const float*)d_in[10];

    float* out = (float*)d_out;
    float* Z1  = out + O_H1;
    char* wsb = (char*)d_ws;

    const bool rot = (ws_size >= GUARD_ROT);

    if (rot) {
        float* c1s = (float*)(wsb + R_C1);
        float* c2s = (float*)(wsb + R_C2);
        const size_t pofs[3] = {R_P0, R_P1, R_P2};
        f16* Phi[3]; f16* Plo[3];
        for (int k = 0; k < 3; ++k) {
            Phi[k] = (f16*)(wsb + pofs[k]);
            Plo[k] = (f16*)(wsb + pofs[k] + 8 * MBY);
        }
        f16* acthi = (f16*)(wsb + R_P3);
        f16* actlo = (f16*)(wsb + R_P3 + 8 * MBY);
        f16* W2hi = (f16*)(wsb + R_W2HI); f16* W2lo = (f16*)(wsb + R_W2LO);
        f16* W3hi = (f16*)(wsb + R_W3HI); f16* W3lo = (f16*)(wsb + R_W3LO);
        f16* W4hi = (f16*)(wsb + R_W4HI); f16* W4lo = (f16*)(wsb + R_W4LO);
        float* halt    = (float*)(wsb + R_MISC);
        float* cont    = halt + 4096;
        float* flagcol = cont + 4096;
        unsigned* ctrl = (unsigned*)(flagcol + 4096);

        f16* xhi = Phi[0]; f16* xlo = Plo[0];
        f16* W1hi = Phi[1]; f16* W1lo = Plo[1];

        k_small_init<<<16, 256, 0, stream>>>(halt, cont, out + O_PSTEP, ctrl);
        k_flagcol<<<16, 256, 0, stream>>>(W_ih1, flagcol);
        k_pack_w<<<2048, 256, 0, stream>>>(W_ih1, W1hi, W1lo, 1025);
        k_pack_w<<<2048, 256, 0, stream>>>(W_ih2, W2hi, W2lo, 1024);
        k_pack_w<<<2048, 256, 0, stream>>>(W_hh2, W3hi, W3lo, 1024);
        k_pack_w<<<2048, 256, 0, stream>>>(W_hh1, W4hi, W4lo, 1024);
        k_split_flat<<<4096, 256, 0, stream>>>(inputs, xhi, xlo);
        k_z1_S<<<512, 512, 0, stream>>>(xhi, xlo, W1hi, W1lo, b_ih1, b_hh1, Z1);

        const int h1in_t[3] = {0, 2, 1}, h2in_t[3] = {1, 0, 2};
        const int h1out_t[3] = {2, 1, 0}, h2out_t[3] = {0, 2, 1};
        for (int s = 0; s < TSTEPS; ++s) {
            const unsigned* cnt_prev = ctrl + (s > 0 ? s - 1 : 0);
            const int i = s % 3;
            k_stepA_S<<<512, 512, 0, stream>>>(
                Z1, W4hi, W4lo, flagcol, c1s,
                Phi[h1in_t[i]], Plo[h1in_t[i]],
                Phi[h1out_t[i]], Plo[h1out_t[i]],
                acthi, actlo, cnt_prev, s);
            k_stepB_S<<<512, 512, 0, stream>>>(
                acthi, actlo, W2hi, W2lo,
                Phi[h2in_t[i]], Plo[h2in_t[i]],
                Phi[h2out_t[i]], Plo[h2out_t[i]],
                W3hi, W3lo, b_ih2, b_hh2, c2s, cnt_prev, s);
            k_haltacc<<<1024, 256, 0, stream>>>(
                Phi[h2out_t[i]], Plo[h2out_t[i]], W_halt, b_halt,
                halt, cont, out + O_PSTEP, ctrl, out + O_ACC, cnt_prev, s);
        }
        k_fin1<<<4096, 256, 0, stream>>>(Phi[0], Plo[0], Phi[1], Plo[1],
                                         Phi[2], Plo[2], c1s, c2s,
                                         halt, cont, ctrl, out);
        k_fin2<<<1, 256, 0, stream>>>(halt, out);
    } else {
        float* c1s = (float*)(wsb + B_C1);
        float* c2s = (float*)(wsb + B_C2);
        f16* h1hi = (f16*)(wsb + B_H1HI);
        f16* h1lo = (f16*)(wsb + B_H1LO);
        f16* h2hi = (f16*)(wsb + B_H2HI);
        f16* h2lo = (f16*)(wsb + B_H2LO);
        f16* acthi = (f16*)(wsb + B_ACTHI);
        f16* actlo = (f16*)(wsb + B_ACTLO);
        f16* W2hi = (f16*)(wsb + B_W2HI); f16* W2lo = (f16*)(wsb + B_W2LO);
        f16* W3hi = (f16*)(wsb + B_W3HI); f16* W3lo = (f16*)(wsb + B_W3LO);
        float* halt    = (float*)(wsb + B_MISC);
        float* cont    = halt + 4096;
        float* flagcol = cont + 4096;
        unsigned* ctrl = (unsigned*)(flagcol + 4096);
        const bool packA = (ws_size >= GUARD_W4);
        f16* W4hi = (f16*)(wsb + B_W4HI);
        f16* W4lo = (f16*)(wsb + B_W4LO);

        f16* xhi = h1hi; f16* xlo = h1lo;
        f16* W1hi = h2hi; f16* W1lo = h2lo;

        k_small_init<<<16, 256, 0, stream>>>(halt, cont, out + O_PSTEP, ctrl);
        k_flagcol<<<16, 256, 0, stream>>>(W_ih1, flagcol);
        k_pack_w<<<2048, 256, 0, stream>>>(W_ih1, W1hi, W1lo, 1025);
        k_pack_w<<<2048, 256, 0, stream>>>(W_ih2, W2hi, W2lo, 1024);
        k_pack_w<<<2048, 256, 0, stream>>>(W_hh2, W3hi, W3lo, 1024);
        if (packA)
            k_pack_w<<<2048, 256, 0, stream>>>(W_hh1, W4hi, W4lo, 1024);
        k_split_flat<<<4096, 256, 0, stream>>>(inputs, xhi, xlo);
        k_z1_L<<<256, 512, 0, stream>>>(xhi, xlo, W1hi, W1lo, b_ih1, b_hh1, Z1);

        for (int s = 0; s < TSTEPS; ++s) {
            const unsigned* cnt_prev = ctrl + (s > 0 ? s - 1 : 0);
            if (packA)
                k_stepA_L<true><<<256, 512, 0, stream>>>(
                    Z1, W_hh1, W4hi, W4lo, flagcol, c1s,
                    h1hi, h1lo, h1hi, h1lo, acthi, actlo, cnt_prev, s);
            else
                k_stepA_L<false><<<256, 512, 0, stream>>>(
                    Z1, W_hh1, W4hi, W4lo, flagcol, c1s,
                    h1hi, h1lo, h1hi, h1lo, acthi, actlo, cnt_prev, s);
            k_stepB_L<<<256, 512, 0, stream>>>(
                acthi, actlo, W2hi, W2lo,
                h2hi, h2lo, h2hi, h2lo,
                W3hi, W3lo, b_ih2, b_hh2, c2s, cnt_prev, s);
            k_haltacc<<<1024, 256, 0, stream>>>(
                h2hi, h2lo, W_halt, b_halt,
                halt, cont, out + O_PSTEP, ctrl, out + O_ACC, cnt_prev, s);
        }
        k_fin1_flat<<<4096, 256, 0, stream>>>(h1hi, h1lo, h2hi, h2lo,
                                              c1s, c2s, halt, cont, out);
        k_fin2<<<1, 256, 0, stream>>>(halt, out);
    }
}

// Round 16
// 1339.091 us; speedup vs baseline: 1.0765x; 1.0765x over previous
//
#include <hip/hip_runtime.h>
#include <cstdint>
#include <cstddef>

// ---------------------------------------------------------------------------
// AdaptiveLSTMBlockWrapper — round 16: REVERT to R14 (best stable config).
// R15's stage-pipelined B spilled (WRITE_SIZE 33->100MB) and regressed.
// R14: race-free state rotation + tiered memory plan; engines are the proven
// R12 (256x256, 1 blk/CU) and R13 (128x256, 2 blk/CU) GEMM cores.
// fp32 GEMM = 3-product split-f16 MFMA; packed-fragment weights (R11).
// ---------------------------------------------------------------------------

typedef _Float16 f16;
typedef f16   f16x8 __attribute__((ext_vector_type(8)));
typedef f16   f16x4 __attribute__((ext_vector_type(4)));
typedef float f32x4 __attribute__((ext_vector_type(4)));

#define TSTEPS 12
#define MBY ((size_t)1 << 20)

// d_out float offsets
#define O_ACC   0u
#define O_H1    4194304u
#define O_C1    8388608u
#define O_H2    12582912u
#define O_C2    16777216u
#define O_PCOST 20971520u
#define O_PSTEP 20971521u

// base3 (R12) ws byte offsets
#define B_C1    ((size_t)0u)
#define B_C2    (16*MBY)
#define B_H1HI  (32*MBY)
#define B_H1LO  (40*MBY)
#define B_H2HI  (48*MBY)
#define B_H2LO  (56*MBY)
#define B_ACTHI (64*MBY)
#define B_ACTLO (72*MBY)
#define B_W2HI  (80*MBY)
#define B_W2LO  (88*MBY)
#define B_W3HI  (96*MBY)
#define B_W3LO  (104*MBY)
#define B_MISC  (112*MBY)
#define B_W4HI  (113*MBY)
#define B_W4LO  (121*MBY)
#define GUARD_W4  (129*MBY)

// rot4 (R13-geom) ws byte offsets
#define R_C1    ((size_t)0u)
#define R_C2    (16*MBY)
#define R_P0    (32*MBY)
#define R_P1    (48*MBY)
#define R_P2    (64*MBY)
#define R_P3    (80*MBY)
#define R_W2HI  (96*MBY)
#define R_W2LO  (104*MBY)
#define R_W3HI  (112*MBY)
#define R_W3LO  (120*MBY)
#define R_MISC  (128*MBY)
#define R_W4HI  (129*MBY)
#define R_W4LO  (137*MBY)
#define GUARD_ROT (146*MBY)

// LDS geometry per engine
#define SEC_ALO_L 32768
#define BUFSZ_L   65536
#define SEC_ALO_S 16384
#define BUFSZ_S   32768

__device__ __forceinline__ float sigmoidf_(float x) { return 1.0f / (1.0f + expf(-x)); }

__device__ __forceinline__ void glds16(const void* g, void* l) {
    __builtin_amdgcn_global_load_lds(
        (const __attribute__((address_space(1))) unsigned int*)g,
        (__attribute__((address_space(3))) unsigned int*)l, 16, 0, 0);
}

__device__ __forceinline__ void block_tile_L(int& m0, int& hc0) {
    const int bid = blockIdx.x;
    const int lid = (bid & 7) * 32 + (bid >> 3);
    m0  = (lid & 15) * 256;
    hc0 = (lid >> 4) * 64;
}
__device__ __forceinline__ void block_tile_S(int& m0, int& hc0) {
    const int bid = blockIdx.x;
    const int lid = (bid & 7) * 64 + (bid >> 3);
    m0  = (lid & 31) * 128;
    hc0 = (lid >> 5) * 64;
}

// ========================= Engine L (R12, 256x256) =========================
template<bool B_PAIR>
__device__ __forceinline__ void passK64_L(
    const f16* __restrict__ Ahi, const f16* __restrict__ Alo,
    const f16* __restrict__ Bhi, const f16* __restrict__ Blo,
    const float* __restrict__ Bf32,
    int m0, int hc0, f32x4 (&acc)[8][4], char* sm)
{
    const int tid = threadIdx.x, lane = tid & 63, wid = tid >> 6;
    const int wm  = (wid >> 2) * 128;
    const int wnb = wid & 3;
    const int l15 = lane & 15, lk = lane >> 4;

    int rbase[8], rx[8];
#pragma unroll
    for (int mf = 0; mf < 8; ++mf) {
        const int row = wm + mf * 16 + l15;
        rbase[mf] = row * 128;
        rx[mf]    = row & 7;
    }

    const int secA = wid >> 2;
    const int j0   = (wid & 3) * 8;
    const int rl = lane >> 3, sl = lane & 7;
    const f16* gaBase = (secA ? Alo : Ahi)
                        + (size_t)(m0 + j0 * 8 + rl) * 1024 + ((sl ^ rl) << 3);
    const int albase0 = secA * SEC_ALO_L + j0 * 1024;

    const float* pB32 = nullptr;
    const f16* pwh = nullptr;
    const f16* pwl = nullptr;
    if constexpr (B_PAIR) {
        const size_t pbase = ((size_t)((hc0 >> 6) * 512 + wnb * 4)) * 512 + (size_t)lane * 8;
        pwh = Bhi + pbase;
        pwl = Blo + pbase;
    } else {
        const int wrow0 = hc0 + wnb * 16 + l15;
        pB32 = Bf32 + (size_t)wrow0 * 1024 + lk * 8;
    }

    f16x8 bh0[4], bl0[4], bh1[4], bl1[4];
    float4 P[8];

    auto issueA = [&](int kt, char* buf) {
#pragma unroll
        for (int i = 0; i < 8; ++i)
            glds16(gaBase + (size_t)i * 8192 + kt * 64, buf + albase0 + i * 1024);
    };
    auto loadBP = [&](int kt, int ks, f16x8 (&H)[4], f16x8 (&L)[4]) {
        const size_t o = (size_t)kt * 16384 + (size_t)ks * 8192;
#pragma unroll
        for (int nf = 0; nf < 4; ++nf) {
            H[nf] = *(const f16x8*)(pwh + o + nf * 512);
            L[nf] = *(const f16x8*)(pwl + o + nf * 512);
        }
    };
    auto loadBM = [&](int kt, int ks) {
#pragma unroll
        for (int nf = 0; nf < 4; ++nf) {
            const float* p = pB32 + (size_t)nf * 1048576 + kt * 64 + ks * 32;
            P[2 * nf]     = *(const float4*)(p);
            P[2 * nf + 1] = *(const float4*)(p + 4);
        }
    };
    auto cvtM = [&](f16x8 (&H)[4], f16x8 (&L)[4]) {
#pragma unroll
        for (int nf = 0; nf < 4; ++nf) {
            const float* f0 = (const float*)&P[2 * nf];
            const float* f1 = (const float*)&P[2 * nf + 1];
            f16x8 h, l;
#pragma unroll
            for (int j = 0; j < 4; ++j) {
                const f16 a = (f16)f0[j];
                h[j] = a; l[j] = (f16)(f0[j] - (float)a);
                const f16 b = (f16)f1[j];
                h[4 + j] = b; l[4 + j] = (f16)(f1[j] - (float)b);
            }
            H[nf] = h; L[nf] = l;
        }
    };
    auto cluster = [&](const f16x8 (&BH)[4], const f16x8 (&BL)[4], int ks, char* bc) {
#pragma unroll
        for (int mg = 0; mg < 4; ++mg) {
            const int o0 = rbase[2 * mg]     + ((((ks << 2) | lk) ^ rx[2 * mg])     << 4);
            const int o1 = rbase[2 * mg + 1] + ((((ks << 2) | lk) ^ rx[2 * mg + 1]) << 4);
            const f16x8 ah0 = *(const f16x8*)(bc + o0);
            const f16x8 al0 = *(const f16x8*)(bc + SEC_ALO_L + o0);
            const f16x8 ah1 = *(const f16x8*)(bc + o1);
            const f16x8 al1 = *(const f16x8*)(bc + SEC_ALO_L + o1);
            __builtin_amdgcn_s_setprio(1);
#pragma unroll
            for (int nf = 0; nf < 4; ++nf) {
                acc[2 * mg][nf]     = __builtin_amdgcn_mfma_f32_16x16x32_f16(ah0, BH[nf], acc[2 * mg][nf], 0, 0, 0);
                acc[2 * mg + 1][nf] = __builtin_amdgcn_mfma_f32_16x16x32_f16(ah1, BH[nf], acc[2 * mg + 1][nf], 0, 0, 0);
            }
#pragma unroll
            for (int nf = 0; nf < 4; ++nf) {
                acc[2 * mg][nf]     = __builtin_amdgcn_mfma_f32_16x16x32_f16(ah0, BL[nf], acc[2 * mg][nf], 0, 0, 0);
                acc[2 * mg + 1][nf] = __builtin_amdgcn_mfma_f32_16x16x32_f16(ah1, BL[nf], acc[2 * mg + 1][nf], 0, 0, 0);
            }
#pragma unroll
            for (int nf = 0; nf < 4; ++nf) {
                acc[2 * mg][nf]     = __builtin_amdgcn_mfma_f32_16x16x32_f16(al0, BH[nf], acc[2 * mg][nf], 0, 0, 0);
                acc[2 * mg + 1][nf] = __builtin_amdgcn_mfma_f32_16x16x32_f16(al1, BH[nf], acc[2 * mg + 1][nf], 0, 0, 0);
            }
            __builtin_amdgcn_s_setprio(0);
        }
    };

    if constexpr (B_PAIR) loadBP(0, 0, bh0, bl0);
    else                  loadBM(0, 0);
    issueA(0, sm);
    asm volatile("s_waitcnt vmcnt(0)" ::: "memory");
    __builtin_amdgcn_s_barrier();
    asm volatile("" ::: "memory");

#pragma unroll 1
    for (int kt = 0; kt < 16; ++kt) {
        char* bc = sm + (kt & 1) * BUFSZ_L;
        char* bn = sm + ((kt + 1) & 1) * BUFSZ_L;
        const bool pre = (kt < 15);

        if constexpr (B_PAIR) {
            loadBP(kt, 1, bh1, bl1);
            if (pre) issueA(kt + 1, bn);
            cluster(bh0, bl0, 0, bc);
            if (pre) asm volatile("s_waitcnt vmcnt(8)" ::: "memory");
            else     asm volatile("s_waitcnt vmcnt(0)" ::: "memory");
            if (pre) loadBP(kt + 1, 0, bh0, bl0);
            cluster(bh1, bl1, 1, bc);
        } else {
            cvtM(bh0, bl0);
            loadBM(kt, 1);
            if (pre) issueA(kt + 1, bn);
            cluster(bh0, bl0, 0, bc);
            if (pre) asm volatile("s_waitcnt vmcnt(8)" ::: "memory");
            else     asm volatile("s_waitcnt vmcnt(0)" ::: "memory");
            cvtM(bh0, bl0);
            if (pre) loadBM(kt + 1, 0);
            cluster(bh0, bl0, 1, bc);
        }
        if (pre) {
            asm volatile("s_waitcnt vmcnt(8)" ::: "memory");
            __builtin_amdgcn_s_barrier();
            asm volatile("" ::: "memory");
        } else {
            asm volatile("s_waitcnt vmcnt(0)" ::: "memory");
        }
    }
}

// ========================= Engine S (R13, 128x256) =========================
template<bool B_PAIR>
__device__ __forceinline__ void passK64_S(
    const f16* __restrict__ Ahi, const f16* __restrict__ Alo,
    const f16* __restrict__ Bhi, const f16* __restrict__ Blo,
    const float* __restrict__ Bf32,
    int m0, int hc0, f32x4 (&acc)[4][4], char* sm)
{
    const int tid = threadIdx.x, lane = tid & 63, wid = tid >> 6;
    const int wm  = (wid >> 2) * 64;
    const int wnb = wid & 3;
    const int l15 = lane & 15, lk = lane >> 4;

    int rbase[4], rx[4];
#pragma unroll
    for (int mf = 0; mf < 4; ++mf) {
        const int row = wm + mf * 16 + l15;
        rbase[mf] = row * 128;
        rx[mf]    = row & 7;
    }

    const int secA = wid >> 2;
    const int j0   = (wid & 3) * 4;
    const int rl = lane >> 3, sl = lane & 7;
    const f16* gaBase = (secA ? Alo : Ahi)
                        + (size_t)(m0 + j0 * 8 + rl) * 1024 + ((sl ^ rl) << 3);
    const int lb0 = secA * SEC_ALO_S + j0 * 1024;

    const float* pB32 = nullptr;
    const f16* pwh = nullptr;
    const f16* pwl = nullptr;
    if constexpr (B_PAIR) {
        const size_t pbase = ((size_t)((hc0 >> 6) * 512 + wnb * 4)) * 512 + (size_t)lane * 8;
        pwh = Bhi + pbase;
        pwl = Blo + pbase;
    } else {
        const int wrow0 = hc0 + wnb * 16 + l15;
        pB32 = Bf32 + (size_t)wrow0 * 1024 + lk * 8;
    }

    auto issueA = [&](int kt, char* buf) {
#pragma unroll
        for (int i = 0; i < 4; ++i)
            glds16(gaBase + (size_t)i * 8192 + kt * 64, buf + lb0 + i * 1024);
    };

    issueA(0, sm);
    asm volatile("s_waitcnt vmcnt(0)" ::: "memory");
    __builtin_amdgcn_s_barrier();
    asm volatile("" ::: "memory");

#pragma unroll 1
    for (int kt = 0; kt < 16; ++kt) {
        char* bc = sm + (kt & 1) * BUFSZ_S;
        char* bn = sm + ((kt + 1) & 1) * BUFSZ_S;
        if (kt < 15) issueA(kt + 1, bn);

#pragma unroll
        for (int ks = 0; ks < 2; ++ks) {
#pragma unroll
            for (int np = 0; np < 2; ++np) {
                f16x8 bh[2], bl[2];
#pragma unroll
                for (int q = 0; q < 2; ++q) {
                    if constexpr (B_PAIR) {
                        const size_t bo = (size_t)kt * 16384 + (size_t)ks * 8192
                                        + (size_t)(2 * np + q) * 512;
                        bh[q] = *(const f16x8*)(pwh + bo);
                        bl[q] = *(const f16x8*)(pwl + bo);
                    } else {
                        const size_t bo = (size_t)(2 * np + q) * 1048576 + kt * 64 + ks * 32;
                        const float* p = pB32 + bo;
                        const float4 v0 = *(const float4*)(p);
                        const float4 v1 = *(const float4*)(p + 4);
                        const float f[8] = {v0.x, v0.y, v0.z, v0.w, v1.x, v1.y, v1.z, v1.w};
                        f16x8 h, l;
#pragma unroll
                        for (int j = 0; j < 8; ++j) {
                            const f16 a = (f16)f[j];
                            h[j] = a; l[j] = (f16)(f[j] - (float)a);
                        }
                        bh[q] = h; bl[q] = l;
                    }
                }
#pragma unroll
                for (int mg = 0; mg < 2; ++mg) {
                    const int o0 = rbase[2 * mg]     + ((((ks << 2) | lk) ^ rx[2 * mg])     << 4);
                    const int o1 = rbase[2 * mg + 1] + ((((ks << 2) | lk) ^ rx[2 * mg + 1]) << 4);
                    const f16x8 ah0 = *(const f16x8*)(bc + o0);
                    const f16x8 al0 = *(const f16x8*)(bc + SEC_ALO_S + o0);
                    const f16x8 ah1 = *(const f16x8*)(bc + o1);
                    const f16x8 al1 = *(const f16x8*)(bc + SEC_ALO_S + o1);
                    __builtin_amdgcn_s_setprio(1);
#pragma unroll
                    for (int q = 0; q < 2; ++q) {
                        acc[2 * mg][2 * np + q]     = __builtin_amdgcn_mfma_f32_16x16x32_f16(ah0, bh[q], acc[2 * mg][2 * np + q], 0, 0, 0);
                        acc[2 * mg + 1][2 * np + q] = __builtin_amdgcn_mfma_f32_16x16x32_f16(ah1, bh[q], acc[2 * mg + 1][2 * np + q], 0, 0, 0);
                    }
#pragma unroll
                    for (int q = 0; q < 2; ++q) {
                        acc[2 * mg][2 * np + q]     = __builtin_amdgcn_mfma_f32_16x16x32_f16(ah0, bl[q], acc[2 * mg][2 * np + q], 0, 0, 0);
                        acc[2 * mg + 1][2 * np + q] = __builtin_amdgcn_mfma_f32_16x16x32_f16(ah1, bl[q], acc[2 * mg + 1][2 * np + q], 0, 0, 0);
                    }
#pragma unroll
                    for (int q = 0; q < 2; ++q) {
                        acc[2 * mg][2 * np + q]     = __builtin_amdgcn_mfma_f32_16x16x32_f16(al0, bh[q], acc[2 * mg][2 * np + q], 0, 0, 0);
                        acc[2 * mg + 1][2 * np + q] = __builtin_amdgcn_mfma_f32_16x16x32_f16(al1, bh[q], acc[2 * mg + 1][2 * np + q], 0, 0, 0);
                    }
                    __builtin_amdgcn_s_setprio(0);
                }
            }
        }
        asm volatile("s_waitcnt vmcnt(0)" ::: "memory");
        if (kt < 15) {
            __builtin_amdgcn_s_barrier();
            asm volatile("" ::: "memory");
        }
    }
}

// ====================== LSTM epilogue helpers (inline) =====================
__device__ __forceinline__ void cellA_epi(
    float p0, float p1, float p2, float p3, int idx, int step,
    float* __restrict__ c1,
    f16* __restrict__ h1ohi, f16* __restrict__ h1olo,
    f16* __restrict__ acthi, f16* __restrict__ actlo)
{
    const float ig = sigmoidf_(p0);
    const float fg = sigmoidf_(p1);
    const float gg = tanhf(p2);
    const float og = sigmoidf_(p3);
    const float cold = (step == 0) ? 0.0f : c1[idx];
    const float cn = fg * cold + ig * gg;
    c1[idx] = cn;
    const float h = og * tanhf(cn);
    const f16 hh = (f16)h;
    const f16 hl = (f16)(h - (float)hh);
    h1ohi[idx] = hh; h1olo[idx] = hl;
    const bool pos = h > 0.0f;
    acthi[idx] = pos ? hh : (f16)0.0f;
    actlo[idx] = pos ? hl : (f16)0.0f;
}
__device__ __forceinline__ void cellB_epi(
    float p0, float p1, float p2, float p3, int idx, int step,
    float* __restrict__ c2,
    f16* __restrict__ h2ohi, f16* __restrict__ h2olo)
{
    const float ig = sigmoidf_(p0);
    const float fg = sigmoidf_(p1);
    const float gg = tanhf(p2);
    const float og = sigmoidf_(p3);
    const float cold = (step == 0) ? 0.0f : c2[idx];
    const float cn = fg * cold + ig * gg;
    c2[idx] = cn;
    const float h = og * tanhf(cn);
    const f16 hh = (f16)h;
    h2ohi[idx] = hh;
    h2olo[idx] = (f16)(h - (float)hh);
}

// ============================ L kernels (R12) ==============================
__global__ __launch_bounds__(512, 2) void k_z1_L(
    const f16* __restrict__ xhi, const f16* __restrict__ xlo,
    const f16* __restrict__ W1hi, const f16* __restrict__ W1lo,
    const float* __restrict__ bih1, const float* __restrict__ bhh1,
    float* __restrict__ Z1)
{
    __shared__ __align__(16) char sm[2 * BUFSZ_L];
    int m0, hc0; block_tile_L(m0, hc0);
    f32x4 acc[8][4];
#pragma unroll
    for (int a = 0; a < 8; ++a)
#pragma unroll
        for (int b = 0; b < 4; ++b) acc[a][b] = (f32x4){0.f, 0.f, 0.f, 0.f};
    passK64_L<true>(xhi, xlo, W1hi, W1lo, nullptr, m0, hc0, acc, sm);

    const int tid = threadIdx.x, lane = tid & 63, wid = tid >> 6;
    const int wm = (wid >> 2) * 128, wnb = wid & 3, l15 = lane & 15, lk = lane >> 4;
    const int hc = hc0 + wnb * 16 + l15;
#pragma unroll
    for (int mf = 0; mf < 8; ++mf)
#pragma unroll
        for (int r = 0; r < 4; ++r) {
            const int row = m0 + wm + mf * 16 + lk * 4 + r;
#pragma unroll
            for (int g = 0; g < 4; ++g) {
                const int R = g * 1024 + hc;
                Z1[(size_t)row * 4096 + R] = acc[mf][g][r] + bih1[R] + bhh1[R];
            }
        }
}

template<bool PACKED>
__global__ __launch_bounds__(512, 2) void k_stepA_L(
    const float* __restrict__ Z1, const float* __restrict__ Whh1,
    const f16* __restrict__ W4hi, const f16* __restrict__ W4lo,
    const float* __restrict__ flagcol, float* __restrict__ c1,
    const f16* __restrict__ h1ihi, const f16* __restrict__ h1ilo,
    f16* __restrict__ h1ohi, f16* __restrict__ h1olo,
    f16* __restrict__ acthi, f16* __restrict__ actlo,
    const unsigned* __restrict__ cnt_prev, int step)
{
    if (step > 0 && cnt_prev[0] == 0u) return;
    __shared__ __align__(16) char sm[2 * BUFSZ_L];
    int m0, hc0; block_tile_L(m0, hc0);
    f32x4 acc[8][4];
#pragma unroll
    for (int a = 0; a < 8; ++a)
#pragma unroll
        for (int b = 0; b < 4; ++b) acc[a][b] = (f32x4){0.f, 0.f, 0.f, 0.f};
    if (step > 0) {
        if constexpr (PACKED)
            passK64_L<true>(h1ihi, h1ilo, W4hi, W4lo, nullptr, m0, hc0, acc, sm);
        else
            passK64_L<false>(h1ihi, h1ilo, nullptr, nullptr, Whh1, m0, hc0, acc, sm);
    }

    const int tid = threadIdx.x, lane = tid & 63, wid = tid >> 6;
    const int wm = (wid >> 2) * 128, wnb = wid & 3, l15 = lane & 15, lk = lane >> 4;
    const int hc = hc0 + wnb * 16 + l15;
#pragma unroll
    for (int mf = 0; mf < 8; ++mf)
#pragma unroll
        for (int r = 0; r < 4; ++r) {
            const int row = m0 + wm + mf * 16 + lk * 4 + r;
            float p[4];
#pragma unroll
            for (int g = 0; g < 4; ++g) {
                const int R = g * 1024 + hc;
                p[g] = acc[mf][g][r] + Z1[(size_t)row * 4096 + R];
                if (step == 0) p[g] += flagcol[R];
            }
            cellA_epi(p[0], p[1], p[2], p[3], row * 1024 + hc, step,
                      c1, h1ohi, h1olo, acthi, actlo);
        }
}

__global__ __launch_bounds__(512, 2) void k_stepB_L(
    const f16* __restrict__ acthi, const f16* __restrict__ actlo,
    const f16* __restrict__ W2hi, const f16* __restrict__ W2lo,
    const f16* __restrict__ h2ihi, const f16* __restrict__ h2ilo,
    f16* __restrict__ h2ohi, f16* __restrict__ h2olo,
    const f16* __restrict__ W3hi, const f16* __restrict__ W3lo,
    const float* __restrict__ bih2, const float* __restrict__ bhh2,
    float* __restrict__ c2,
    const unsigned* __restrict__ cnt_prev, int step)
{
    if (step > 0 && cnt_prev[0] == 0u) return;
    __shared__ __align__(16) char sm[2 * BUFSZ_L];
    int m0, hc0; block_tile_L(m0, hc0);
    f32x4 acc[8][4];
#pragma unroll
    for (int a = 0; a < 8; ++a)
#pragma unroll
        for (int b = 0; b < 4; ++b) acc[a][b] = (f32x4){0.f, 0.f, 0.f, 0.f};
    passK64_L<true>(acthi, actlo, W2hi, W2lo, nullptr, m0, hc0, acc, sm);
    if (step > 0)
        passK64_L<true>(h2ihi, h2ilo, W3hi, W3lo, nullptr, m0, hc0, acc, sm);

    const int tid = threadIdx.x, lane = tid & 63, wid = tid >> 6;
    const int wm = (wid >> 2) * 128, wnb = wid & 3, l15 = lane & 15, lk = lane >> 4;
    const int hc = hc0 + wnb * 16 + l15;
#pragma unroll
    for (int mf = 0; mf < 8; ++mf)
#pragma unroll
        for (int r = 0; r < 4; ++r) {
            const int row = m0 + wm + mf * 16 + lk * 4 + r;
            float p[4];
#pragma unroll
            for (int g = 0; g < 4; ++g) {
                const int R = g * 1024 + hc;
                p[g] = acc[mf][g][r] + bih2[R] + bhh2[R];
            }
            cellB_epi(p[0], p[1], p[2], p[3], row * 1024 + hc, step, c2, h2ohi, h2olo);
        }
}

// ============================ S kernels (R13) ==============================
__global__ __launch_bounds__(512, 4) void k_z1_S(
    const f16* __restrict__ xhi, const f16* __restrict__ xlo,
    const f16* __restrict__ W1hi, const f16* __restrict__ W1lo,
    const float* __restrict__ bih1, const float* __restrict__ bhh1,
    float* __restrict__ Z1)
{
    __shared__ __align__(16) char sm[2 * BUFSZ_S];
    int m0, hc0; block_tile_S(m0, hc0);
    f32x4 acc[4][4];
#pragma unroll
    for (int a = 0; a < 4; ++a)
#pragma unroll
        for (int b = 0; b < 4; ++b) acc[a][b] = (f32x4){0.f, 0.f, 0.f, 0.f};
    passK64_S<true>(xhi, xlo, W1hi, W1lo, nullptr, m0, hc0, acc, sm);

    const int tid = threadIdx.x, lane = tid & 63, wid = tid >> 6;
    const int wm = (wid >> 2) * 64, wnb = wid & 3, l15 = lane & 15, lk = lane >> 4;
    const int hc = hc0 + wnb * 16 + l15;
#pragma unroll
    for (int mf = 0; mf < 4; ++mf)
#pragma unroll
        for (int r = 0; r < 4; ++r) {
            const int row = m0 + wm + mf * 16 + lk * 4 + r;
#pragma unroll
            for (int g = 0; g < 4; ++g) {
                const int R = g * 1024 + hc;
                Z1[(size_t)row * 4096 + R] = acc[mf][g][r] + bih1[R] + bhh1[R];
            }
        }
}

__global__ __launch_bounds__(512, 4) void k_stepA_S(
    const float* __restrict__ Z1,
    const f16* __restrict__ W4hi, const f16* __restrict__ W4lo,
    const float* __restrict__ flagcol, float* __restrict__ c1,
    const f16* __restrict__ h1ihi, const f16* __restrict__ h1ilo,
    f16* __restrict__ h1ohi, f16* __restrict__ h1olo,
    f16* __restrict__ acthi, f16* __restrict__ actlo,
    const unsigned* __restrict__ cnt_prev, int step)
{
    if (step > 0 && cnt_prev[0] == 0u) return;
    __shared__ __align__(16) char sm[2 * BUFSZ_S];
    int m0, hc0; block_tile_S(m0, hc0);
    f32x4 acc[4][4];
#pragma unroll
    for (int a = 0; a < 4; ++a)
#pragma unroll
        for (int b = 0; b < 4; ++b) acc[a][b] = (f32x4){0.f, 0.f, 0.f, 0.f};
    if (step > 0)
        passK64_S<true>(h1ihi, h1ilo, W4hi, W4lo, nullptr, m0, hc0, acc, sm);

    const int tid = threadIdx.x, lane = tid & 63, wid = tid >> 6;
    const int wm = (wid >> 2) * 64, wnb = wid & 3, l15 = lane & 15, lk = lane >> 4;
    const int hc = hc0 + wnb * 16 + l15;
#pragma unroll
    for (int mf = 0; mf < 4; ++mf)
#pragma unroll
        for (int r = 0; r < 4; ++r) {
            const int row = m0 + wm + mf * 16 + lk * 4 + r;
            float p[4];
#pragma unroll
            for (int g = 0; g < 4; ++g) {
                const int R = g * 1024 + hc;
                p[g] = acc[mf][g][r] + Z1[(size_t)row * 4096 + R];
                if (step == 0) p[g] += flagcol[R];
            }
            cellA_epi(p[0], p[1], p[2], p[3], row * 1024 + hc, step,
                      c1, h1ohi, h1olo, acthi, actlo);
        }
}

__global__ __launch_bounds__(512, 4) void k_stepB_S(
    const f16* __restrict__ acthi, const f16* __restrict__ actlo,
    const f16* __restrict__ W2hi, const f16* __restrict__ W2lo,
    const f16* __restrict__ h2ihi, const f16* __restrict__ h2ilo,
    f16* __restrict__ h2ohi, f16* __restrict__ h2olo,
    const f16* __restrict__ W3hi, const f16* __restrict__ W3lo,
    const float* __restrict__ bih2, const float* __restrict__ bhh2,
    float* __restrict__ c2,
    const unsigned* __restrict__ cnt_prev, int step)
{
    if (step > 0 && cnt_prev[0] == 0u) return;
    __shared__ __align__(16) char sm[2 * BUFSZ_S];
    int m0, hc0; block_tile_S(m0, hc0);
    f32x4 acc[4][4];
#pragma unroll
    for (int a = 0; a < 4; ++a)
#pragma unroll
        for (int b = 0; b < 4; ++b) acc[a][b] = (f32x4){0.f, 0.f, 0.f, 0.f};
    passK64_S<true>(acthi, actlo, W2hi, W2lo, nullptr, m0, hc0, acc, sm);
    if (step > 0)
        passK64_S<true>(h2ihi, h2ilo, W3hi, W3lo, nullptr, m0, hc0, acc, sm);

    const int tid = threadIdx.x, lane = tid & 63, wid = tid >> 6;
    const int wm = (wid >> 2) * 64, wnb = wid & 3, l15 = lane & 15, lk = lane >> 4;
    const int hc = hc0 + wnb * 16 + l15;
#pragma unroll
    for (int mf = 0; mf < 4; ++mf)
#pragma unroll
        for (int r = 0; r < 4; ++r) {
            const int row = m0 + wm + mf * 16 + lk * 4 + r;
            float p[4];
#pragma unroll
            for (int g = 0; g < 4; ++g) {
                const int R = g * 1024 + hc;
                p[g] = acc[mf][g][r] + bih2[R] + bhh2[R];
            }
            cellB_epi(p[0], p[1], p[2], p[3], row * 1024 + hc, step, c2, h2ohi, h2olo);
        }
}

// ============================ shared kernels ===============================
__global__ __launch_bounds__(256) void k_haltacc(
    const f16* __restrict__ h2hi, const f16* __restrict__ h2lo,
    const float* __restrict__ Whalt, const float* __restrict__ bhalt,
    float* __restrict__ halt, float* __restrict__ cont,
    float* __restrict__ ponder_out, unsigned* __restrict__ ctrl,
    float* __restrict__ acc_out,
    const unsigned* __restrict__ cnt_prev, int step)
{
    if (step > 0 && cnt_prev[0] == 0u) return;
    const int lane = threadIdx.x & 63;
    const int b = blockIdx.x * 4 + (threadIdx.x >> 6);
    const size_t base = (size_t)b * 1024;
    float sum = 0.0f;
    for (int k = lane; k < 1024; k += 64)
        sum += ((float)h2hi[base + k] + (float)h2lo[base + k]) * Whalt[k];
#pragma unroll
    for (int off = 32; off > 0; off >>= 1) sum += __shfl_down(sum, off, 64);
    float co = 0.0f;
    if (lane == 0) {
        const float sh = sigmoidf_(sum + bhalt[0]);
        if (cont[b] != 0.0f) {
            const float hn = halt[b] + sh;
            const bool ending = hn > 0.99f;
            co = sh + (ending ? (1.0f - hn) : 0.0f);
            halt[b] = hn;
            if (!ending) {
                ponder_out[b] += 1.0f;
                atomicAdd(&ctrl[step], 1u);
            } else {
                cont[b] = 0.0f;
            }
        }
        if (b == 0) ctrl[12] = (unsigned)(step + 1);
    }
    co = __shfl(co, 0, 64);
    if (step == 0 || co != 0.0f) {
        float4* dst = (float4*)(acc_out + base);
        const f16x4* hi4 = (const f16x4*)(h2hi + base);
        const f16x4* lo4 = (const f16x4*)(h2lo + base);
#pragma unroll
        for (int j = 0; j < 4; ++j) {
            const int i = lane + 64 * j;
            const f16x4 hv = hi4[i];
            const f16x4 lv = lo4[i];
            float4 d = (step == 0) ? (float4){0.f, 0.f, 0.f, 0.f} : dst[i];
            d.x = fmaf(co, (float)hv[0] + (float)lv[0], d.x);
            d.y = fmaf(co, (float)hv[1] + (float)lv[1], d.y);
            d.z = fmaf(co, (float)hv[2] + (float)lv[2], d.z);
            d.w = fmaf(co, (float)hv[3] + (float)lv[3], d.w);
            dst[i] = d;
        }
    }
}

__global__ __launch_bounds__(256) void k_small_init(
    float* __restrict__ halt, float* __restrict__ cont,
    float* __restrict__ ponder_out, unsigned* __restrict__ ctrl)
{
    const int b = blockIdx.x * 256 + threadIdx.x;
    if (b < 4096) { halt[b] = 0.0f; cont[b] = 1.0f; ponder_out[b] = 0.0f; }
    if (b < 16) ctrl[b] = 0u;
}

__global__ __launch_bounds__(256) void k_split_flat(
    const float* __restrict__ src, f16* __restrict__ hi, f16* __restrict__ lo)
{
    const size_t i = ((size_t)blockIdx.x * 256 + threadIdx.x) * 4;
    const float4 v = *(const float4*)(src + i);
    const f16 s0 = (f16)v.x, s1 = (f16)v.y, s2 = (f16)v.z, s3 = (f16)v.w;
    const f16x4 hv = {s0, s1, s2, s3};
    const f16x4 lw = {(f16)(v.x - (float)s0), (f16)(v.y - (float)s1),
                      (f16)(v.z - (float)s2), (f16)(v.w - (float)s3)};
    *(f16x4*)(hi + i) = hv;
    *(f16x4*)(lo + i) = lw;
}

__global__ __launch_bounds__(256) void k_pack_w(
    const float* __restrict__ src, f16* __restrict__ hi, f16* __restrict__ lo,
    int stride)
{
    const size_t t = (size_t)blockIdx.x * 256 + threadIdx.x;
    const int lane = (int)(t & 63);
    const size_t C = t >> 6;
    const int nf  = (int)(C & 3);
    const int wnb = (int)((C >> 2) & 3);
    const int ks  = (int)((C >> 4) & 1);
    const int kt  = (int)((C >> 5) & 15);
    const int T   = (int)(C >> 9);
    const int row = nf * 1024 + T * 64 + wnb * 16 + (lane & 15);
    const int k0  = kt * 64 + ks * 32 + (lane >> 4) * 8;
    const float* s = src + (size_t)row * stride + k0;
    f16x8 h, l;
#pragma unroll
    for (int j = 0; j < 8; ++j) {
        const float v = s[j];
        const f16 a = (f16)v;
        h[j] = a; l[j] = (f16)(v - (float)a);
    }
    *(f16x8*)(hi + t * 8) = h;
    *(f16x8*)(lo + t * 8) = l;
}

__global__ __launch_bounds__(256) void k_flagcol(
    const float* __restrict__ Wih1, float* __restrict__ flagcol)
{
    const int r = blockIdx.x * 256 + threadIdx.x;
    if (r < 4096) flagcol[r] = Wih1[(size_t)r * 1025 + 1024];
}

// fin1: select final h1/h2 slots from ctrl[12] (rotation tables)
__global__ __launch_bounds__(256) void k_fin1(
    const f16* __restrict__ a0h, const f16* __restrict__ a0l,
    const f16* __restrict__ a1h, const f16* __restrict__ a1l,
    const f16* __restrict__ a2h, const f16* __restrict__ a2l,
    const float* __restrict__ c1s, const float* __restrict__ c2s,
    const float* __restrict__ halt, const float* __restrict__ cont,
    const unsigned* __restrict__ ctrl, float* __restrict__ out)
{
    const int j = ((int)ctrl[12] - 1) % 3;
    const f16* h1h = (j == 0) ? a2h : (j == 1) ? a1h : a0h;
    const f16* h1l = (j == 0) ? a2l : (j == 1) ? a1l : a0l;
    const f16* h2h = (j == 0) ? a0h : (j == 1) ? a2h : a1h;
    const f16* h2l = (j == 0) ? a0l : (j == 1) ? a2l : a1l;
    const int b = blockIdx.x;
    const float rem = (cont[b] != 0.0f) ? (1.0f - halt[b]) : 0.0f;
    const int base = b * 1024;
    for (int i = threadIdx.x; i < 1024; i += 256) {
        const float h1v = (float)h1h[base + i] + (float)h1l[base + i];
        const float h2v = (float)h2h[base + i] + (float)h2l[base + i];
        out[O_H1 + base + i] = h1v;
        out[O_C1 + base + i] = c1s[base + i];
        out[O_H2 + base + i] = h2v;
        out[O_C2 + base + i] = c2s[base + i];
        if (rem != 0.0f) out[O_ACC + base + i] += rem * h2v;
    }
}

// in-place path fin1 (single h1/h2 buffers, no selection)
__global__ __launch_bounds__(256) void k_fin1_flat(
    const f16* __restrict__ h1h, const f16* __restrict__ h1l,
    const f16* __restrict__ h2h, const f16* __restrict__ h2l,
    const float* __restrict__ c1s, const float* __restrict__ c2s,
    const float* __restrict__ halt, const float* __restrict__ cont,
    float* __restrict__ out)
{
    const int b = blockIdx.x;
    const float rem = (cont[b] != 0.0f) ? (1.0f - halt[b]) : 0.0f;
    const int base = b * 1024;
    for (int i = threadIdx.x; i < 1024; i += 256) {
        const float h1v = (float)h1h[base + i] + (float)h1l[base + i];
        const float h2v = (float)h2h[base + i] + (float)h2l[base + i];
        out[O_H1 + base + i] = h1v;
        out[O_C1 + base + i] = c1s[base + i];
        out[O_H2 + base + i] = h2v;
        out[O_C2 + base + i] = c2s[base + i];
        if (rem != 0.0f) out[O_ACC + base + i] += rem * h2v;
    }
}

__global__ __launch_bounds__(256) void k_fin2(
    const float* __restrict__ halt, float* __restrict__ out)
{
    __shared__ float red[256];
    float s = 0.0f;
    for (int i = threadIdx.x; i < 4096; i += 256) s += halt[i];
    red[threadIdx.x] = s;
    __syncthreads();
    for (int w = 128; w > 0; w >>= 1) {
        if (threadIdx.x < w) red[threadIdx.x] += red[threadIdx.x + w];
        __syncthreads();
    }
    if (threadIdx.x == 0) out[O_PCOST] = -0.01f * (red[0] * (1.0f / 4096.0f));
}

// ================================= host ====================================
extern "C" void kernel_launch(void* const* d_in, const int* in_sizes, int n_in,
                              void* d_out, int out_size, void* d_ws, size_t ws_size,
                              hipStream_t stream) {
    const float* inputs = (const float*)d_in[0];
    const float* W_ih1  = (const float*)d_in[1];
    const float* W_hh1  = (const float*)d_in[2];
    const float* b_ih1  = (const float*)d_in[3];
    const float* b_hh1  = (const float*)d_in[4];
    const float* W_ih2  = (const float*)d_in[5];
    const float* W_hh2  = (const float*)d_in[6];
    const float* b_ih2  = (const float*)d_in[7];
    const float* b_hh2  = (const float*)d_in[8];
    const float* W_halt = (const float*)d_in[9];
    const float* b_halt = (const float*)d_in[10];

    float* out = (float*)d_out;
    float* Z1  = out + O_H1;
    char* wsb = (char*)d_ws;

    const bool rot = (ws_size >= GUARD_ROT);

    if (rot) {
        // -------- R13 geometry + rotation + packed Whh1 (race-free) --------
        float* c1s = (float*)(wsb + R_C1);
        float* c2s = (float*)(wsb + R_C2);
        const size_t pofs[3] = {R_P0, R_P1, R_P2};
        f16* Phi[3]; f16* Plo[3];
        for (int k = 0; k < 3; ++k) {
            Phi[k] = (f16*)(wsb + pofs[k]);
            Plo[k] = (f16*)(wsb + pofs[k] + 8 * MBY);
        }
        f16* acthi = (f16*)(wsb + R_P3);
        f16* actlo = (f16*)(wsb + R_P3 + 8 * MBY);
        f16* W2hi = (f16*)(wsb + R_W2HI); f16* W2lo = (f16*)(wsb + R_W2LO);
        f16* W3hi = (f16*)(wsb + R_W3HI); f16* W3lo = (f16*)(wsb + R_W3LO);
        f16* W4hi = (f16*)(wsb + R_W4HI); f16* W4lo = (f16*)(wsb + R_W4LO);
        float* halt    = (float*)(wsb + R_MISC);
        float* cont    = halt + 4096;
        float* flagcol = cont + 4096;
        unsigned* ctrl = (unsigned*)(flagcol + 4096);

        // z1 temporaries in dead slots: x -> P0, W1 -> P1
        f16* xhi = Phi[0]; f16* xlo = Plo[0];
        f16* W1hi = Phi[1]; f16* W1lo = Plo[1];

        k_small_init<<<16, 256, 0, stream>>>(halt, cont, out + O_PSTEP, ctrl);
        k_flagcol<<<16, 256, 0, stream>>>(W_ih1, flagcol);
        k_pack_w<<<2048, 256, 0, stream>>>(W_ih1, W1hi, W1lo, 1025);
        k_pack_w<<<2048, 256, 0, stream>>>(W_ih2, W2hi, W2lo, 1024);
        k_pack_w<<<2048, 256, 0, stream>>>(W_hh2, W3hi, W3lo, 1024);
        k_pack_w<<<2048, 256, 0, stream>>>(W_hh1, W4hi, W4lo, 1024);
        k_split_flat<<<4096, 256, 0, stream>>>(inputs, xhi, xlo);
        k_z1_S<<<512, 512, 0, stream>>>(xhi, xlo, W1hi, W1lo, b_ih1, b_hh1, Z1);

        const int h1in_t[3] = {0, 2, 1}, h2in_t[3] = {1, 0, 2};
        const int h1out_t[3] = {2, 1, 0}, h2out_t[3] = {0, 2, 1};
        for (int s = 0; s < TSTEPS; ++s) {
            const unsigned* cnt_prev = ctrl + (s > 0 ? s - 1 : 0);
            const int i = s % 3;
            k_stepA_S<<<512, 512, 0, stream>>>(
                Z1, W4hi, W4lo, flagcol, c1s,
                Phi[h1in_t[i]], Plo[h1in_t[i]],
                Phi[h1out_t[i]], Plo[h1out_t[i]],
                acthi, actlo, cnt_prev, s);
            k_stepB_S<<<512, 512, 0, stream>>>(
                acthi, actlo, W2hi, W2lo,
                Phi[h2in_t[i]], Plo[h2in_t[i]],
                Phi[h2out_t[i]], Plo[h2out_t[i]],
                W3hi, W3lo, b_ih2, b_hh2, c2s, cnt_prev, s);
            k_haltacc<<<1024, 256, 0, stream>>>(
                Phi[h2out_t[i]], Plo[h2out_t[i]], W_halt, b_halt,
                halt, cont, out + O_PSTEP, ctrl, out + O_ACC, cnt_prev, s);
        }
        k_fin1<<<4096, 256, 0, stream>>>(Phi[0], Plo[0], Phi[1], Plo[1],
                                         Phi[2], Plo[2], c1s, c2s,
                                         halt, cont, ctrl, out);
        k_fin2<<<1, 256, 0, stream>>>(halt, out);
    } else {
        // -------- exact R12: 256x256 engine, in-place state (proven) -------
        float* c1s = (float*)(wsb + B_C1);
        float* c2s = (float*)(wsb + B_C2);
        f16* h1hi = (f16*)(wsb + B_H1HI);
        f16* h1lo = (f16*)(wsb + B_H1LO);
        f16* h2hi = (f16*)(wsb + B_H2HI);
        f16* h2lo = (f16*)(wsb + B_H2LO);
        f16* acthi = (f16*)(wsb + B_ACTHI);
        f16* actlo = (f16*)(wsb + B_ACTLO);
        f16* W2hi = (f16*)(wsb + B_W2HI); f16* W2lo = (f16*)(wsb + B_W2LO);
        f16* W3hi = (f16*)(wsb + B_W3HI); f16* W3lo = (f16*)(wsb + B_W3LO);
        float* halt    = (float*)(wsb + B_MISC);
        float* cont    = halt + 4096;
        float* flagcol = cont + 4096;
        unsigned* ctrl = (unsigned*)(flagcol + 4096);
        const bool packA = (ws_size >= GUARD_W4);
        f16* W4hi = (f16*)(wsb + B_W4HI);
        f16* W4lo = (f16*)(wsb + B_W4LO);

        f16* xhi = h1hi; f16* xlo = h1lo;
        f16* W1hi = h2hi; f16* W1lo = h2lo;

        k_small_init<<<16, 256, 0, stream>>>(halt, cont, out + O_PSTEP, ctrl);
        k_flagcol<<<16, 256, 0, stream>>>(W_ih1, flagcol);
        k_pack_w<<<2048, 256, 0, stream>>>(W_ih1, W1hi, W1lo, 1025);
        k_pack_w<<<2048, 256, 0, stream>>>(W_ih2, W2hi, W2lo, 1024);
        k_pack_w<<<2048, 256, 0, stream>>>(W_hh2, W3hi, W3lo, 1024);
        if (packA)
            k_pack_w<<<2048, 256, 0, stream>>>(W_hh1, W4hi, W4lo, 1024);
        k_split_flat<<<4096, 256, 0, stream>>>(inputs, xhi, xlo);
        k_z1_L<<<256, 512, 0, stream>>>(xhi, xlo, W1hi, W1lo, b_ih1, b_hh1, Z1);

        for (int s = 0; s < TSTEPS; ++s) {
            const unsigned* cnt_prev = ctrl + (s > 0 ? s - 1 : 0);
            if (packA)
                k_stepA_L<true><<<256, 512, 0, stream>>>(
                    Z1, W_hh1, W4hi, W4lo, flagcol, c1s,
                    h1hi, h1lo, h1hi, h1lo, acthi, actlo, cnt_prev, s);
            else
                k_stepA_L<false><<<256, 512, 0, stream>>>(
                    Z1, W_hh1, W4hi, W4lo, flagcol, c1s,
                    h1hi, h1lo, h1hi, h1lo, acthi, actlo, cnt_prev, s);
            k_stepB_L<<<256, 512, 0, stream>>>(
                acthi, actlo, W2hi, W2lo,
                h2hi, h2lo, h2hi, h2lo,
                W3hi, W3lo, b_ih2, b_hh2, c2s, cnt_prev, s);
            k_haltacc<<<1024, 256, 0, stream>>>(
                h2hi, h2lo, W_halt, b_halt,
                halt, cont, out + O_PSTEP, ctrl, out + O_ACC, cnt_prev, s);
        }
        k_fin1_flat<<<4096, 256, 0, stream>>>(h1hi, h1lo, h2hi, h2lo,
                                              c1s, c2s, halt, cont, out);
        k_fin2<<<1, 256, 0, stream>>>(halt, out);
    }
}